// Round 12
// baseline (754.416 us; speedup 1.0000x reference)
//
#include <hip/hip_runtime.h>
#include <hip/hip_bf16.h>

#define N_EDGES 800000
#define M_BLK   64
#define NBLK    (N_EDGES / M_BLK)   // 12500
#define N_NODES 50000

typedef __attribute__((ext_vector_type(8))) _Float16 half8;
typedef __attribute__((ext_vector_type(4))) float    f32x4;

// ws layout (bytes):
//   0        wt1s  [128][192] f16   (49152)
//   49152    wt1v  [128][192] f16   (49152)
//   98304    wt2s  [64][128]  f16   (16384)
//   114688   wt2v  [32][128]  f16   (8192)
//   122880   w1s192[128] f32        (512)
//   123392   w1v192[128] f32        (512)
//   131072   feat16 [50000][64] f16 (6400000)
#define WS_FEAT16_OFF 131072
#define WS_NEEDED     (WS_FEAT16_OFF + (size_t)N_NODES * 64 * 2)

__global__ void prep_kernel(const float* __restrict__ W1s, const float* __restrict__ W1v,
                            const float* __restrict__ W2s, const float* __restrict__ W2v,
                            _Float16* __restrict__ wt1s, _Float16* __restrict__ wt1v,
                            _Float16* __restrict__ wt2s, _Float16* __restrict__ wt2v,
                            float* __restrict__ w1s192, float* __restrict__ w1v192)
{
    int idx = blockIdx.x * blockDim.x + threadIdx.x;
    if (idx < 128 * 192) {
        int c = idx / 192, k = idx % 192;
        wt1s[idx] = (_Float16)W1s[k * 128 + c];
        wt1v[idx] = (_Float16)W1v[k * 128 + c];
        return;
    }
    int i2 = idx - 128 * 192;
    if (i2 >= 0 && i2 < 64 * 128) {
        int c = i2 / 128, k = i2 % 128;
        wt2s[i2] = (_Float16)W2s[k * 64 + c];
        return;
    }
    int i3 = idx - (128 * 192 + 64 * 128);
    if (i3 >= 0 && i3 < 32 * 128) {
        int c = i3 / 128, k = i3 % 128;
        wt2v[i3] = (_Float16)W2v[k * 32 + c];
        return;
    }
    int i4 = idx - (128 * 192 + 64 * 128 + 32 * 128);
    if (i4 >= 0 && i4 < 128) {
        w1s192[i4] = W1s[192 * 128 + i4];
        w1v192[i4] = W1v[192 * 128 + i4];
    }
}

__global__ void prep_feat16(const float* __restrict__ feat, _Float16* __restrict__ feat16)
{
    int idx = blockIdx.x * blockDim.x + threadIdx.x;
    if (idx < N_NODES * 32) {
        float2 v = ((const float2*)feat)[idx];
        feat16[idx * 2]     = (_Float16)v.x;
        feat16[idx * 2 + 1] = (_Float16)v.y;
    }
}

// XOR-swizzled LDS address (proven R2): 16B chunk index ^= (row & 7).
__device__ __forceinline__ void* xsw(char* base, int row, int byte_in_row, int row_bytes)
{
    int chunk = byte_in_row >> 4;
    int sw    = ((chunk ^ (row & 7)) << 4) | (byte_in_row & 15);
    return (void*)(base + row * row_bytes + sw);
}

// ---------------- fused edge-MLP kernel (R12: 1-barrier) ----------------
// 8 waves / 64 edges per block. Layer-1 re-split: wave (rg=w>>1, chh=w&1)
// computes rows rg*16..+16 x cols chh*64..+64, so each lane's A-fragment is
// ONE edge row gathered DIRECTLY from feat16 into MFMA registers (4 scattered
// 16B loads; diff in-register). Removes: LDS X stage (27 LDS ops/lane),
// barriers A and C, ~250 VALU/lane of swizzle math. ONE barrier between
// layer-1 epilogue and layer-2. Stores byte-identical to R11 (coalesced --
// R10's store fragmentation cost 2x WRITE). LDS = Hs+Hv = 32KB.
__global__ void edge_mlp_kernel(
    const int*   __restrict__ endpoints,
    const float* __restrict__ edge_len,
    const float* __restrict__ theta,
    const _Float16* __restrict__ feat16,
    const float* __restrict__ b1s, const float* __restrict__ b2s,
    const float* __restrict__ b1v, const float* __restrict__ b2v,
    const _Float16* __restrict__ wt1s, const _Float16* __restrict__ wt1v,
    const _Float16* __restrict__ wt2s, const _Float16* __restrict__ wt2v,
    const float* __restrict__ w1s192, const float* __restrict__ w1v192,
    float* __restrict__ h0, float* __restrict__ v0)
{
    __shared__ char lds[32768];
    char* ldsHs = lds;            // Hs [64]x256B swizzled
    char* ldsHv = lds + 16384;    // Hv [64]x256B swizzled

    const int t   = threadIdx.x;
    const int blk = blockIdx.x;
    const int w   = t >> 6;
    const int l   = t & 63;
    const int lr  = l & 15;
    const int lk  = l >> 4;
    const int rg  = w >> 1;       // row group: edges rg*16..+16 (also layer-2 rt2)
    const int chh = w & 1;        // layer-1 col half (also layer-2 ch)
    const int base = blk * M_BLK;

    // ---- direct per-lane fragment gather: edge row = rg*16 + lr ----
    const int erow = rg * 16 + lr;
    int2 ep = ((const int2*)endpoints)[base + erow];
    const _Float16* fi = feat16 + (size_t)ep.x * 64 + lk * 8;
    const _Float16* fj = feat16 + (size_t)ep.y * 64 + lk * 8;
    half8 pi_lo = *(const half8*)(fi);        // ks0: fi[lk*8..+8]
    half8 pi_hi = *(const half8*)(fi + 32);   // ks1: fi[32+lk*8..+8]
    half8 pj_lo = *(const half8*)(fj);        // ks2
    half8 pj_hi = *(const half8*)(fj + 32);   // ks3
    half8 pd_lo, pd_hi;                        // ks4, ks5
#pragma unroll
    for (int q = 0; q < 8; ++q) {
        _Float16 d0 = pi_lo[q] - pj_lo[q];
        _Float16 d1 = pi_hi[q] - pj_hi[q];
        pd_lo[q] = d0 < (_Float16)0 ? (_Float16)(-d0) : d0;
        pd_hi[q] = d1 < (_Float16)0 ? (_Float16)(-d1) : d1;
    }

    // len/theta for rows rg*16 + lk*4 + r (broadcast float4)
    float4 len4 = *(const float4*)(edge_len + base + rg * 16 + lk * 4);
    float4 th4  = *(const float4*)(theta    + base + rg * 16 + lk * 4);

    // ---- layer 1: 6 ks x 4 ct x {scalar, vector} MFMA (ks-outer) ----
    f32x4 accS[4], accV[4];
#pragma unroll
    for (int ct = 0; ct < 4; ++ct) {
        accS[ct] = (f32x4){0.f, 0.f, 0.f, 0.f};
        accV[ct] = (f32x4){0.f, 0.f, 0.f, 0.f};
    }
    // B-frag byte addr: (chh*64 + ct*16 + lr)*384 + ks*64 + lk*16
    const char* pws = (const char*)wt1s + (chh * 64 + lr) * 384 + lk * 16;
    const char* pwv = (const char*)wt1v + (chh * 64 + lr) * 384 + lk * 16;
#pragma unroll
    for (int ks = 0; ks < 6; ++ks) {
        half8 a = (ks == 0) ? pi_lo : (ks == 1) ? pi_hi : (ks == 2) ? pj_lo
                : (ks == 3) ? pj_hi : (ks == 4) ? pd_lo : pd_hi;
#pragma unroll
        for (int ct = 0; ct < 4; ++ct) {
            half8 bs = *(const half8*)(pws + ct * 6144 + ks * 64);
            half8 bv = *(const half8*)(pwv + ct * 6144 + ks * 64);
            accS[ct] = __builtin_amdgcn_mfma_f32_16x16x32_f16(a, bs, accS[ct], 0, 0, 0);
            accV[ct] = __builtin_amdgcn_mfma_f32_16x16x32_f16(a, bv, accV[ct], 0, 0, 0);
        }
    }

    // ---- layer-1 epilogue -> Hs/Hv (swizzled LDS) ----
    float lv[4] = {len4.x, len4.y, len4.z, len4.w};
#pragma unroll
    for (int ct = 0; ct < 4; ++ct) {
        int col = chh * 64 + ct * 16 + lr;
        float bs_ = b1s[col], bv_ = b1v[col];
        float ws_ = w1s192[col], wv_ = w1v192[col];
#pragma unroll
        for (int r = 0; r < 4; ++r) {
            int row = rg * 16 + lk * 4 + r;
            float hs = accS[ct][r] + bs_ + lv[r] * ws_;
            float hv = accV[ct][r] + bv_ + lv[r] * wv_;
            *(_Float16*)xsw(ldsHs, row, col * 2, 256) = (_Float16)fmaxf(hs, 0.f);
            *(_Float16*)xsw(ldsHv, row, col * 2, 256) = (_Float16)fmaxf(hv, 0.f);
        }
    }
    __syncthreads();   // THE barrier: Hs/Hv visible

    // ---- layer 2 + global stores (byte-identical to R11 PH3) ----
    {
        const float b2s_a = b2s[chh * 32 + lr];
        const float b2s_b = b2s[chh * 32 + 16 + lr];
        const float b2v_c = b2v[chh * 16 + lr];
        f32x4 acc2[2];
        acc2[0] = (f32x4){0.f, 0.f, 0.f, 0.f};
        acc2[1] = (f32x4){0.f, 0.f, 0.f, 0.f};
        f32x4 accV2 = (f32x4){0.f, 0.f, 0.f, 0.f};
        const int cv = chh * 16 + lr;
#pragma unroll
        for (int ks = 0; ks < 4; ++ks) {
            half8 a2 = *(half8*)xsw(ldsHs, rg * 16 + lr, ks * 64 + lk * 16, 256);
#pragma unroll
            for (int ct = 0; ct < 2; ++ct) {
                int c2 = chh * 32 + ct * 16 + lr;
                half8 b = *reinterpret_cast<const half8*>(wt2s + c2 * 128 + ks * 32 + lk * 8);
                acc2[ct] = __builtin_amdgcn_mfma_f32_16x16x32_f16(a2, b, acc2[ct], 0, 0, 0);
            }
            half8 av  = *(half8*)xsw(ldsHv, rg * 16 + lr, ks * 64 + lk * 16, 256);
            half8 bv2 = *reinterpret_cast<const half8*>(wt2v + cv * 128 + ks * 32 + lk * 8);
            accV2 = __builtin_amdgcn_mfma_f32_16x16x32_f16(av, bv2, accV2, 0, 0, 0);
        }
        float dx[4], dy[4];
        {
            float thv[4] = {th4.x, th4.y, th4.z, th4.w};
#pragma unroll
            for (int r = 0; r < 4; ++r) { dx[r] = cosf(thv[r]); dy[r] = sinf(thv[r]); }
        }
#pragma unroll
        for (int ct = 0; ct < 2; ++ct) {
            int c2 = chh * 32 + ct * 16 + lr;
            float bias = ct ? b2s_b : b2s_a;
#pragma unroll
            for (int r = 0; r < 4; ++r) {
                int row = rg * 16 + lk * 4 + r;
                h0[(size_t)(base + row) * 64 + c2] = acc2[ct][r] + bias;
            }
        }
#pragma unroll
        for (int r = 0; r < 4; ++r) {
            int row = rg * 16 + lk * 4 + r;
            float amp = accV2[r] + b2v_c;
            *reinterpret_cast<float2*>(v0 + ((size_t)(base + row) * 32 + cv) * 2) =
                make_float2(amp * dx[r], amp * dy[r]);
        }
    }
}

// -------- fallback (R11 f32-gather kernel, verbatim) if ws too small --------
__global__ void edge_mlp_kernel_f32(
    const int*   __restrict__ endpoints,
    const float* __restrict__ edge_len,
    const float* __restrict__ theta,
    const float* __restrict__ feat,
    const float* __restrict__ b1s, const float* __restrict__ b2s,
    const float* __restrict__ b1v, const float* __restrict__ b2v,
    const _Float16* __restrict__ wt1s, const _Float16* __restrict__ wt1v,
    const _Float16* __restrict__ wt2s, const _Float16* __restrict__ wt2v,
    const float* __restrict__ w1s192, const float* __restrict__ w1v192,
    float* __restrict__ h0, float* __restrict__ v0)
{
    __shared__ char lds[40960];
    char* ldsX  = lds;
    char* ldsHs = lds + 24576;
    char* ldsHv = lds;

    const int t   = threadIdx.x;
    const int blk = blockIdx.x;
    const int w   = t >> 6;
    const int l   = t & 63;
    const int lr  = l & 15;
    const int lk  = l >> 4;
    const int e   = t >> 3;
    const int f0q = t & 7;
    const int base = blk * M_BLK;
    const int c1 = w * 16 + lr;
    const int rt2 = w >> 1;
    const int ch  = w & 1;

    float4 len_a[4];
#pragma unroll
    for (int rt = 0; rt < 4; ++rt)
        len_a[rt] = *(const float4*)(edge_len + base + rt * 16 + lk * 4);
    float4 th4 = *(const float4*)(theta + base + rt2 * 16 + lk * 4);

    {
        int2 ep0 = ((const int2*)endpoints)[base + e];
        const float* pfi = feat + (size_t)ep0.x * 64 + f0q * 8;
        const float* pfj = feat + (size_t)ep0.y * 64 + f0q * 8;
        float4 fi0 = ((const float4*)pfi)[0], fi1 = ((const float4*)pfi)[1];
        float4 fj0 = ((const float4*)pfj)[0], fj1 = ((const float4*)pfj)[1];
        float ai[8] = {fi0.x, fi0.y, fi0.z, fi0.w, fi1.x, fi1.y, fi1.z, fi1.w};
        float bj[8] = {fj0.x, fj0.y, fj0.z, fj0.w, fj1.x, fj1.y, fj1.z, fj1.w};
        half8 pi, pj, pd;
#pragma unroll
        for (int q = 0; q < 8; ++q) {
            pi[q] = (_Float16)ai[q];
            pj[q] = (_Float16)bj[q];
            pd[q] = (_Float16)fabsf(ai[q] - bj[q]);
        }
        *(half8*)xsw(ldsX, e, f0q * 16, 384)       = pi;
        *(half8*)xsw(ldsX, e, 128 + f0q * 16, 384) = pj;
        *(half8*)xsw(ldsX, e, 256 + f0q * 16, 384) = pd;
    }

    const float b1s_c   = b1s[c1];
    const float b1v_c   = b1v[c1];
    const float w192s_c = w1s192[c1];
    const float w192v_c = w1v192[c1];
    const float b2s_a = b2s[ch * 32 + lr];
    const float b2s_b = b2s[ch * 32 + 16 + lr];
    const float b2v_c = b2v[ch * 16 + lr];

    __syncthreads();

    {
        const char* pws = (const char*)wt1s + c1 * 384 + lk * 16;
        f32x4 acc[4];
#pragma unroll
        for (int rt = 0; rt < 4; ++rt) acc[rt] = (f32x4){0.f, 0.f, 0.f, 0.f};
        half8 bw = *reinterpret_cast<const half8*>(pws);
#pragma unroll
        for (int ks = 0; ks < 6; ++ks) {
            half8 bwn = bw;
            if (ks < 5) bwn = *reinterpret_cast<const half8*>(pws + (ks + 1) * 64);
#pragma unroll
            for (int rt = 0; rt < 4; ++rt) {
                half8 a = *(half8*)xsw(ldsX, rt * 16 + lr, ks * 64 + lk * 16, 384);
                acc[rt] = __builtin_amdgcn_mfma_f32_16x16x32_f16(a, bw, acc[rt], 0, 0, 0);
            }
            bw = bwn;
        }
#pragma unroll
        for (int rt = 0; rt < 4; ++rt) {
            float lv[4] = {len_a[rt].x, len_a[rt].y, len_a[rt].z, len_a[rt].w};
#pragma unroll
            for (int r = 0; r < 4; ++r) {
                int row = rt * 16 + lk * 4 + r;
                float hs = acc[rt][r] + b1s_c + lv[r] * w192s_c;
                *(_Float16*)xsw(ldsHs, row, c1 * 2, 256) = (_Float16)fmaxf(hs, 0.f);
            }
        }
    }

    f32x4 accv[4];
    {
        const char* pwv = (const char*)wt1v + c1 * 384 + lk * 16;
#pragma unroll
        for (int rt = 0; rt < 4; ++rt) accv[rt] = (f32x4){0.f, 0.f, 0.f, 0.f};
        half8 bw = *reinterpret_cast<const half8*>(pwv);
#pragma unroll
        for (int ks = 0; ks < 6; ++ks) {
            half8 bwn = bw;
            if (ks < 5) bwn = *reinterpret_cast<const half8*>(pwv + (ks + 1) * 64);
#pragma unroll
            for (int rt = 0; rt < 4; ++rt) {
                half8 a = *(half8*)xsw(ldsX, rt * 16 + lr, ks * 64 + lk * 16, 384);
                accv[rt] = __builtin_amdgcn_mfma_f32_16x16x32_f16(a, bw, accv[rt], 0, 0, 0);
            }
            bw = bwn;
        }
    }
    __syncthreads();

#pragma unroll
    for (int rt = 0; rt < 4; ++rt) {
        float lv[4] = {len_a[rt].x, len_a[rt].y, len_a[rt].z, len_a[rt].w};
#pragma unroll
        for (int r = 0; r < 4; ++r) {
            int row = rt * 16 + lk * 4 + r;
            float hv = accv[rt][r] + b1v_c + lv[r] * w192v_c;
            *(_Float16*)xsw(ldsHv, row, c1 * 2, 256) = (_Float16)fmaxf(hv, 0.f);
        }
    }
    __syncthreads();

    {
        f32x4 acc2[2];
        acc2[0] = (f32x4){0.f, 0.f, 0.f, 0.f};
        acc2[1] = (f32x4){0.f, 0.f, 0.f, 0.f};
        f32x4 accV = (f32x4){0.f, 0.f, 0.f, 0.f};
        const int cv = ch * 16 + lr;
#pragma unroll
        for (int ks = 0; ks < 4; ++ks) {
            half8 a2 = *(half8*)xsw(ldsHs, rt2 * 16 + lr, ks * 64 + lk * 16, 256);
#pragma unroll
            for (int ct = 0; ct < 2; ++ct) {
                int c2 = ch * 32 + ct * 16 + lr;
                half8 b = *reinterpret_cast<const half8*>(wt2s + c2 * 128 + ks * 32 + lk * 8);
                acc2[ct] = __builtin_amdgcn_mfma_f32_16x16x32_f16(a2, b, acc2[ct], 0, 0, 0);
            }
            half8 av  = *(half8*)xsw(ldsHv, rt2 * 16 + lr, ks * 64 + lk * 16, 256);
            half8 bv2 = *reinterpret_cast<const half8*>(wt2v + cv * 128 + ks * 32 + lk * 8);
            accV = __builtin_amdgcn_mfma_f32_16x16x32_f16(av, bv2, accV, 0, 0, 0);
        }
        float dx[4], dy[4];
        {
            float thv[4] = {th4.x, th4.y, th4.z, th4.w};
#pragma unroll
            for (int r = 0; r < 4; ++r) { dx[r] = cosf(thv[r]); dy[r] = sinf(thv[r]); }
        }
#pragma unroll
        for (int ct = 0; ct < 2; ++ct) {
            int c2 = ch * 32 + ct * 16 + lr;
            float bias = ct ? b2s_b : b2s_a;
#pragma unroll
            for (int r = 0; r < 4; ++r) {
                int row = rt2 * 16 + lk * 4 + r;
                h0[(size_t)(base + row) * 64 + c2] = acc2[ct][r] + bias;
            }
        }
#pragma unroll
        for (int r = 0; r < 4; ++r) {
            int row = rt2 * 16 + lk * 4 + r;
            float amp = accV[r] + b2v_c;
            *reinterpret_cast<float2*>(v0 + ((size_t)(base + row) * 32 + cv) * 2) =
                make_float2(amp * dx[r], amp * dy[r]);
        }
    }
}

extern "C" void kernel_launch(void* const* d_in, const int* in_sizes, int n_in,
                              void* d_out, int out_size, void* d_ws, size_t ws_size,
                              hipStream_t stream)
{
    const int*   endpoints = (const int*)d_in[0];
    const float* edge_len  = (const float*)d_in[1];
    const float* theta     = (const float*)d_in[2];
    const float* feat      = (const float*)d_in[3];
    const float* W1s       = (const float*)d_in[4];
    const float* b1s       = (const float*)d_in[5];
    const float* W2s       = (const float*)d_in[6];
    const float* b2s       = (const float*)d_in[7];
    const float* W1v       = (const float*)d_in[8];
    const float* b1v       = (const float*)d_in[9];
    const float* W2v       = (const float*)d_in[10];
    const float* b2v       = (const float*)d_in[11];

    char* ws = (char*)d_ws;
    _Float16* wt1s   = (_Float16*)(ws);
    _Float16* wt1v   = (_Float16*)(ws + 49152);
    _Float16* wt2s   = (_Float16*)(ws + 98304);
    _Float16* wt2v   = (_Float16*)(ws + 114688);
    float*    w1s192 = (float*)(ws + 122880);
    float*    w1v192 = (float*)(ws + 123392);
    _Float16* feat16 = (_Float16*)(ws + WS_FEAT16_OFF);

    prep_kernel<<<145, 256, 0, stream>>>(W1s, W1v, W2s, W2v,
                                         wt1s, wt1v, wt2s, wt2v, w1s192, w1v192);

    float* h0 = (float*)d_out;
    float* v0 = h0 + (size_t)N_EDGES * 64;

    if (ws_size >= WS_NEEDED) {
        prep_feat16<<<(N_NODES * 32 + 255) / 256, 256, 0, stream>>>(feat, feat16);
        edge_mlp_kernel<<<NBLK, 512, 0, stream>>>(endpoints, edge_len, theta, feat16,
                                                  b1s, b2s, b1v, b2v,
                                                  wt1s, wt1v, wt2s, wt2v,
                                                  w1s192, w1v192, h0, v0);
    } else {
        edge_mlp_kernel_f32<<<NBLK, 512, 0, stream>>>(endpoints, edge_len, theta, feat,
                                                      b1s, b2s, b1v, b2v,
                                                      wt1s, wt1v, wt2s, wt2v,
                                                      w1s192, w1v192, h0, v0);
    }
}

// Round 13
// 342.557 us; speedup vs baseline: 2.2023x; 2.2023x over previous
//
#include <hip/hip_runtime.h>
#include <hip/hip_bf16.h>

#define N_EDGES 800000
#define M_BLK   64
#define NBLK    (N_EDGES / M_BLK)   // 12500
#define N_NODES 50000

typedef __attribute__((ext_vector_type(8))) _Float16 half8;
typedef __attribute__((ext_vector_type(4))) float    f32x4;

// ws layout (bytes):
//   0        wt1s  [128][192] f16   (49152)
//   49152    wt1v  [128][192] f16   (49152)
//   98304    wt2s  [64][128]  f16   (16384)
//   114688   wt2v  [32][128]  f16   (8192)
//   122880   w1s192[128] f32        (512)
//   123392   w1v192[128] f32        (512)
//   131072   feat16 [50000][64] f16 (6400000)
#define WS_FEAT16_OFF 131072
#define WS_NEEDED     (WS_FEAT16_OFF + (size_t)N_NODES * 64 * 2)

__global__ void prep_kernel(const float* __restrict__ W1s, const float* __restrict__ W1v,
                            const float* __restrict__ W2s, const float* __restrict__ W2v,
                            _Float16* __restrict__ wt1s, _Float16* __restrict__ wt1v,
                            _Float16* __restrict__ wt2s, _Float16* __restrict__ wt2v,
                            float* __restrict__ w1s192, float* __restrict__ w1v192)
{
    int idx = blockIdx.x * blockDim.x + threadIdx.x;
    if (idx < 128 * 192) {
        int c = idx / 192, k = idx % 192;
        wt1s[idx] = (_Float16)W1s[k * 128 + c];
        wt1v[idx] = (_Float16)W1v[k * 128 + c];
        return;
    }
    int i2 = idx - 128 * 192;
    if (i2 >= 0 && i2 < 64 * 128) {
        int c = i2 / 128, k = i2 % 128;
        wt2s[i2] = (_Float16)W2s[k * 64 + c];
        return;
    }
    int i3 = idx - (128 * 192 + 64 * 128);
    if (i3 >= 0 && i3 < 32 * 128) {
        int c = i3 / 128, k = i3 % 128;
        wt2v[i3] = (_Float16)W2v[k * 32 + c];
        return;
    }
    int i4 = idx - (128 * 192 + 64 * 128 + 32 * 128);
    if (i4 >= 0 && i4 < 128) {
        w1s192[i4] = W1s[192 * 128 + i4];
        w1v192[i4] = W1v[192 * 128 + i4];
    }
}

__global__ void prep_feat16(const float* __restrict__ feat, _Float16* __restrict__ feat16)
{
    int idx = blockIdx.x * blockDim.x + threadIdx.x;
    if (idx < N_NODES * 32) {
        float2 v = ((const float2*)feat)[idx];
        feat16[idx * 2]     = (_Float16)v.x;
        feat16[idx * 2 + 1] = (_Float16)v.y;
    }
}

// XOR-swizzled LDS address (proven R2): 16B chunk index ^= (row & 7).
__device__ __forceinline__ void* xsw(char* base, int row, int byte_in_row, int row_bytes)
{
    int chunk = byte_in_row >> 4;
    int sw    = ((chunk ^ (row & 7)) << 4) | (byte_in_row & 15);
    return (void*)(base + row * row_bytes + sw);
}

// ---------------- fused edge-MLP kernel (R13) ----------------
// R6 structure (best known, 330us): one 64-edge tile/block, 8 waves, 3
// barriers, X(24K)+Hs(16K)+Len/Dir LDS (~42KB -> 3 blocks/CU), Hv aliases
// dead X, loop-free no-spill shape. R13 latency fixes inside that shape:
//  - ALL 6 weight fragments loaded up-front per pass (one L2 latency wait
//    instead of six depth-1 stalls of ~300cyc each)
//  - PH1b's weight loads issued BEFORE the Hs epilogue (epilogue hides them)
//  - s_setprio(1) around MFMA clusters (phase diversity across 3 resident
//    blocks)
//  - f16 gather table (R9): halves gather instrs, same proven numerics
__global__ void edge_mlp_kernel(
    const int*   __restrict__ endpoints,
    const float* __restrict__ edge_len,
    const float* __restrict__ theta,
    const _Float16* __restrict__ feat16,
    const float* __restrict__ b1s, const float* __restrict__ b2s,
    const float* __restrict__ b1v, const float* __restrict__ b2v,
    const _Float16* __restrict__ wt1s, const _Float16* __restrict__ wt1v,
    const _Float16* __restrict__ wt2s, const _Float16* __restrict__ wt2v,
    const float* __restrict__ w1s192, const float* __restrict__ w1v192,
    float* __restrict__ h0, float* __restrict__ v0)
{
    __shared__ char   ldsX [M_BLK * 384];   // X [64]x384B swizzled; Hv aliases [0:16K) later
    __shared__ char   ldsHs[M_BLK * 256];   // Hs [64]x256B swizzled
    __shared__ float  Len[M_BLK];
    __shared__ float2 Dir[M_BLK];

    const int t   = threadIdx.x;
    const int blk = blockIdx.x;
    const int w   = t >> 6;
    const int l   = t & 63;
    const int lr  = l & 15;
    const int lk  = l >> 4;
    const int e   = t >> 3;         // edge within tile (0..63)
    const int f0q = t & 7;          // 16B (8-half) feature chunk
    const int base = blk * M_BLK;

    const int c1 = w * 16 + lr;     // layer-1 hidden column owned by this lane

    // ---- gather (f16 table, 2 scattered 16B loads) + diff -> LDS X ----
    {
        int2 ep0 = ((const int2*)endpoints)[base + e];
        half8 pi = *(const half8*)(feat16 + (size_t)ep0.x * 64 + f0q * 8);
        half8 pj = *(const half8*)(feat16 + (size_t)ep0.y * 64 + f0q * 8);
        half8 pd;
#pragma unroll
        for (int q = 0; q < 8; ++q) {
            _Float16 d = pi[q] - pj[q];
            pd[q] = d < (_Float16)0 ? (_Float16)(-d) : d;
        }
        *(half8*)xsw(ldsX, e, f0q * 16, 384)       = pi;
        *(half8*)xsw(ldsX, e, 128 + f0q * 16, 384) = pj;
        *(half8*)xsw(ldsX, e, 256 + f0q * 16, 384) = pd;
        if (t < M_BLK)          Len[t] = edge_len[base + t];
        else if (t < 2 * M_BLK) {
            float th = theta[base + (t - M_BLK)];
            Dir[t - M_BLK] = make_float2(cosf(th), sinf(th));
        }
    }

    const float b1s_c   = b1s[c1];
    const float b1v_c   = b1v[c1];
    const float w192s_c = w1s192[c1];
    const float w192v_c = w1v192[c1];
    const int rt2 = w >> 1;
    const int ch  = w & 1;
    const float b2s_a = b2s[ch * 32 + lr];
    const float b2s_b = b2s[ch * 32 + 16 + lr];
    const float b2v_c = b2v[ch * 16 + lr];

    __syncthreads();   // A: X/Len/Dir visible

    // ---- PH1a: scalar-MLP layer 1 -- ALL 6 weight frags up-front ----
    {
        const char* pws = (const char*)wt1s + c1 * 384 + lk * 16;
        half8 bw[6];
#pragma unroll
        for (int ks = 0; ks < 6; ++ks)
            bw[ks] = *reinterpret_cast<const half8*>(pws + ks * 64);
        f32x4 acc[4];
#pragma unroll
        for (int rt = 0; rt < 4; ++rt) acc[rt] = (f32x4){0.f, 0.f, 0.f, 0.f};
        __builtin_amdgcn_s_setprio(1);
#pragma unroll
        for (int ks = 0; ks < 6; ++ks)
#pragma unroll
            for (int rt = 0; rt < 4; ++rt) {
                half8 a = *(half8*)xsw(ldsX, rt * 16 + lr, ks * 64 + lk * 16, 384);
                acc[rt] = __builtin_amdgcn_mfma_f32_16x16x32_f16(a, bw[ks], acc[rt], 0, 0, 0);
            }
        __builtin_amdgcn_s_setprio(0);
        // Hs epilogue (separate region: overlaps PH1b below)
#pragma unroll
        for (int rt = 0; rt < 4; ++rt) {
            float4 l4 = *reinterpret_cast<const float4*>(&Len[rt * 16 + lk * 4]);
            float lv[4] = {l4.x, l4.y, l4.z, l4.w};
#pragma unroll
            for (int r = 0; r < 4; ++r) {
                int row = rt * 16 + lk * 4 + r;
                float hs = acc[rt][r] + b1s_c + lv[r] * w192s_c;
                *(_Float16*)xsw(ldsHs, row, c1 * 2, 256) = (_Float16)fmaxf(hs, 0.f);
            }
        }
    }

    // ---- PH1b: vector-MLP layer 1 (weights pre-issued above epilogue) ----
    f32x4 accv[4];
    {
        const char* pwv = (const char*)wt1v + c1 * 384 + lk * 16;
        half8 bw[6];
#pragma unroll
        for (int ks = 0; ks < 6; ++ks)
            bw[ks] = *reinterpret_cast<const half8*>(pwv + ks * 64);
#pragma unroll
        for (int rt = 0; rt < 4; ++rt) accv[rt] = (f32x4){0.f, 0.f, 0.f, 0.f};
        __builtin_amdgcn_s_setprio(1);
#pragma unroll
        for (int ks = 0; ks < 6; ++ks)
#pragma unroll
            for (int rt = 0; rt < 4; ++rt) {
                half8 a = *(half8*)xsw(ldsX, rt * 16 + lr, ks * 64 + lk * 16, 384);
                accv[rt] = __builtin_amdgcn_mfma_f32_16x16x32_f16(a, bw[ks], accv[rt], 0, 0, 0);
            }
        __builtin_amdgcn_s_setprio(0);
    }
    __syncthreads();   // B: all X reads + Hs writes complete

    // ---- PH1b epilogue: Hv onto dead X region ----
    char* ldsHv = ldsX;
#pragma unroll
    for (int rt = 0; rt < 4; ++rt) {
        float4 l4 = *reinterpret_cast<const float4*>(&Len[rt * 16 + lk * 4]);
        float lv[4] = {l4.x, l4.y, l4.z, l4.w};
#pragma unroll
        for (int r = 0; r < 4; ++r) {
            int row = rt * 16 + lk * 4 + r;
            float hv = accv[rt][r] + b1v_c + lv[r] * w192v_c;
            *(_Float16*)xsw(ldsHv, row, c1 * 2, 256) = (_Float16)fmaxf(hv, 0.f);
        }
    }
    __syncthreads();   // C: Hv visible

    // ---- PH3: layer 2 + global stores ----
    {
        f32x4 acc2[2];
        acc2[0] = (f32x4){0.f, 0.f, 0.f, 0.f};
        acc2[1] = (f32x4){0.f, 0.f, 0.f, 0.f};
        f32x4 accV = (f32x4){0.f, 0.f, 0.f, 0.f};
        const int cv = ch * 16 + lr;
        // pre-issue all layer-2 A-fragments (LDS) and first weight trio
        half8 a2[4], av[4];
#pragma unroll
        for (int ks = 0; ks < 4; ++ks) {
            a2[ks] = *(half8*)xsw(ldsHs, rt2 * 16 + lr, ks * 64 + lk * 16, 256);
            av[ks] = *(half8*)xsw(ldsHv, rt2 * 16 + lr, ks * 64 + lk * 16, 256);
        }
        __builtin_amdgcn_s_setprio(1);
#pragma unroll
        for (int ks = 0; ks < 4; ++ks) {
#pragma unroll
            for (int ct = 0; ct < 2; ++ct) {
                int c2 = ch * 32 + ct * 16 + lr;
                half8 b = *reinterpret_cast<const half8*>(wt2s + c2 * 128 + ks * 32 + lk * 8);
                acc2[ct] = __builtin_amdgcn_mfma_f32_16x16x32_f16(a2[ks], b, acc2[ct], 0, 0, 0);
            }
            half8 bv2 = *reinterpret_cast<const half8*>(wt2v + cv * 128 + ks * 32 + lk * 8);
            accV = __builtin_amdgcn_mfma_f32_16x16x32_f16(av[ks], bv2, accV, 0, 0, 0);
        }
        __builtin_amdgcn_s_setprio(0);
#pragma unroll
        for (int ct = 0; ct < 2; ++ct) {
            int c2 = ch * 32 + ct * 16 + lr;
            float bias = ct ? b2s_b : b2s_a;
#pragma unroll
            for (int r = 0; r < 4; ++r) {
                int row = rt2 * 16 + lk * 4 + r;
                h0[(size_t)(base + row) * 64 + c2] = acc2[ct][r] + bias;
            }
        }
#pragma unroll
        for (int r = 0; r < 4; ++r) {
            int row = rt2 * 16 + lk * 4 + r;
            float amp = accV[r] + b2v_c;
            float2 d = Dir[row];
            *reinterpret_cast<float2*>(v0 + ((size_t)(base + row) * 32 + cv) * 2) =
                make_float2(amp * d.x, amp * d.y);
        }
    }
}

// -------- fallback (f32 gather, R8-exact proven structure) --------
__global__ void edge_mlp_kernel_f32(
    const int*   __restrict__ endpoints,
    const float* __restrict__ edge_len,
    const float* __restrict__ theta,
    const float* __restrict__ feat,
    const float* __restrict__ b1s, const float* __restrict__ b2s,
    const float* __restrict__ b1v, const float* __restrict__ b2v,
    const _Float16* __restrict__ wt1s, const _Float16* __restrict__ wt1v,
    const _Float16* __restrict__ wt2s, const _Float16* __restrict__ wt2v,
    const float* __restrict__ w1s192, const float* __restrict__ w1v192,
    float* __restrict__ h0, float* __restrict__ v0)
{
    __shared__ char   lds[32768];
    __shared__ float  Len[M_BLK];
    __shared__ float2 Dir[M_BLK];
    char* ldsX  = lds;
    char* ldsHs = lds;
    char* ldsHv = lds + 16384;

    const int t   = threadIdx.x;
    const int blk = blockIdx.x;
    const int w   = t >> 6;
    const int l   = t & 63;
    const int lr  = l & 15;
    const int lk  = l >> 4;
    const int e   = t >> 3;
    const int f0q = t & 7;
    const int base = blk * M_BLK;
    const int c1 = w * 16 + lr;

    {
        int2 ep0 = ((const int2*)endpoints)[base + e];
        const float* pfi = feat + (size_t)ep0.x * 64 + f0q * 8;
        const float* pfj = feat + (size_t)ep0.y * 64 + f0q * 8;
        float4 fi0 = ((const float4*)pfi)[0], fi1 = ((const float4*)pfi)[1];
        float4 fj0 = ((const float4*)pfj)[0], fj1 = ((const float4*)pfj)[1];
        float ai[8] = {fi0.x, fi0.y, fi0.z, fi0.w, fi1.x, fi1.y, fi1.z, fi1.w};
        float bj[8] = {fj0.x, fj0.y, fj0.z, fj0.w, fj1.x, fj1.y, fj1.z, fj1.w};
        half8 pi, pj, pd;
#pragma unroll
        for (int q = 0; q < 8; ++q) {
            pi[q] = (_Float16)ai[q];
            pj[q] = (_Float16)bj[q];
            pd[q] = (_Float16)fabsf(ai[q] - bj[q]);
        }
        *(half8*)xsw(ldsX, e, f0q * 16, 384)       = pi;
        *(half8*)xsw(ldsX, e, 128 + f0q * 16, 384) = pj;
        *(half8*)xsw(ldsX, e, 256 + f0q * 16, 384) = pd;
        if (t < M_BLK)          Len[t] = edge_len[base + t];
        else if (t < 2 * M_BLK) {
            float th = theta[base + (t - M_BLK)];
            Dir[t - M_BLK] = make_float2(cosf(th), sinf(th));
        }
    }

    const float b1s_c   = b1s[c1];
    const float b1v_c   = b1v[c1];
    const float w192s_c = w1s192[c1];
    const float w192v_c = w1v192[c1];
    const int rt2 = w >> 1;
    const int ch  = w & 1;
    const float b2s_a = b2s[ch * 32 + lr];
    const float b2s_b = b2s[ch * 32 + 16 + lr];
    const float b2v_c = b2v[ch * 16 + lr];

    __syncthreads();

    f32x4 accs[4], accv[4];
    {
        const char* pws = (const char*)wt1s + c1 * 384 + lk * 16;
        const char* pwv = (const char*)wt1v + c1 * 384 + lk * 16;
#pragma unroll
        for (int rt = 0; rt < 4; ++rt) {
            accs[rt] = (f32x4){0.f, 0.f, 0.f, 0.f};
            accv[rt] = (f32x4){0.f, 0.f, 0.f, 0.f};
        }
        half8 bs = *reinterpret_cast<const half8*>(pws);
        half8 bv = *reinterpret_cast<const half8*>(pwv);
#pragma unroll
        for (int ks = 0; ks < 6; ++ks) {
            half8 bsn = bs, bvn = bv;
            if (ks < 5) {
                bsn = *reinterpret_cast<const half8*>(pws + (ks + 1) * 64);
                bvn = *reinterpret_cast<const half8*>(pwv + (ks + 1) * 64);
            }
#pragma unroll
            for (int rt = 0; rt < 4; ++rt) {
                half8 a = *(half8*)xsw(ldsX, rt * 16 + lr, ks * 64 + lk * 16, 384);
                accs[rt] = __builtin_amdgcn_mfma_f32_16x16x32_f16(a, bs, accs[rt], 0, 0, 0);
                accv[rt] = __builtin_amdgcn_mfma_f32_16x16x32_f16(a, bv, accv[rt], 0, 0, 0);
            }
            bs = bsn; bv = bvn;
        }
    }
    __syncthreads();

#pragma unroll
    for (int rt = 0; rt < 4; ++rt) {
        float4 l4 = *reinterpret_cast<const float4*>(&Len[rt * 16 + lk * 4]);
        float lv[4] = {l4.x, l4.y, l4.z, l4.w};
#pragma unroll
        for (int r = 0; r < 4; ++r) {
            int row = rt * 16 + lk * 4 + r;
            float hs = accs[rt][r] + b1s_c + lv[r] * w192s_c;
            float hv = accv[rt][r] + b1v_c + lv[r] * w192v_c;
            *(_Float16*)xsw(ldsHs, row, c1 * 2, 256) = (_Float16)fmaxf(hs, 0.f);
            *(_Float16*)xsw(ldsHv, row, c1 * 2, 256) = (_Float16)fmaxf(hv, 0.f);
        }
    }
    __syncthreads();

    {
        f32x4 acc2[2];
        acc2[0] = (f32x4){0.f, 0.f, 0.f, 0.f};
        acc2[1] = (f32x4){0.f, 0.f, 0.f, 0.f};
        f32x4 accV = (f32x4){0.f, 0.f, 0.f, 0.f};
        const int cv = ch * 16 + lr;
#pragma unroll
        for (int ks = 0; ks < 4; ++ks) {
            half8 a2 = *(half8*)xsw(ldsHs, rt2 * 16 + lr, ks * 64 + lk * 16, 256);
#pragma unroll
            for (int ct = 0; ct < 2; ++ct) {
                int c2 = ch * 32 + ct * 16 + lr;
                half8 b = *reinterpret_cast<const half8*>(wt2s + c2 * 128 + ks * 32 + lk * 8);
                acc2[ct] = __builtin_amdgcn_mfma_f32_16x16x32_f16(a2, b, acc2[ct], 0, 0, 0);
            }
            half8 av  = *(half8*)xsw(ldsHv, rt2 * 16 + lr, ks * 64 + lk * 16, 256);
            half8 bv2 = *reinterpret_cast<const half8*>(wt2v + cv * 128 + ks * 32 + lk * 8);
            accV = __builtin_amdgcn_mfma_f32_16x16x32_f16(av, bv2, accV, 0, 0, 0);
        }
#pragma unroll
        for (int ct = 0; ct < 2; ++ct) {
            int c2 = ch * 32 + ct * 16 + lr;
            float bias = ct ? b2s_b : b2s_a;
#pragma unroll
            for (int r = 0; r < 4; ++r) {
                int row = rt2 * 16 + lk * 4 + r;
                h0[(size_t)(base + row) * 64 + c2] = acc2[ct][r] + bias;
            }
        }
#pragma unroll
        for (int r = 0; r < 4; ++r) {
            int row = rt2 * 16 + lk * 4 + r;
            float amp = accV[r] + b2v_c;
            float2 d = Dir[row];
            *reinterpret_cast<float2*>(v0 + ((size_t)(base + row) * 32 + cv) * 2) =
                make_float2(amp * d.x, amp * d.y);
        }
    }
}

extern "C" void kernel_launch(void* const* d_in, const int* in_sizes, int n_in,
                              void* d_out, int out_size, void* d_ws, size_t ws_size,
                              hipStream_t stream)
{
    const int*   endpoints = (const int*)d_in[0];
    const float* edge_len  = (const float*)d_in[1];
    const float* theta     = (const float*)d_in[2];
    const float* feat      = (const float*)d_in[3];
    const float* W1s       = (const float*)d_in[4];
    const float* b1s       = (const float*)d_in[5];
    const float* W2s       = (const float*)d_in[6];
    const float* b2s       = (const float*)d_in[7];
    const float* W1v       = (const float*)d_in[8];
    const float* b1v       = (const float*)d_in[9];
    const float* W2v       = (const float*)d_in[10];
    const float* b2v       = (const float*)d_in[11];

    char* ws = (char*)d_ws;
    _Float16* wt1s   = (_Float16*)(ws);
    _Float16* wt1v   = (_Float16*)(ws + 49152);
    _Float16* wt2s   = (_Float16*)(ws + 98304);
    _Float16* wt2v   = (_Float16*)(ws + 114688);
    float*    w1s192 = (float*)(ws + 122880);
    float*    w1v192 = (float*)(ws + 123392);
    _Float16* feat16 = (_Float16*)(ws + WS_FEAT16_OFF);

    prep_kernel<<<145, 256, 0, stream>>>(W1s, W1v, W2s, W2v,
                                         wt1s, wt1v, wt2s, wt2v, w1s192, w1v192);

    float* h0 = (float*)d_out;
    float* v0 = h0 + (size_t)N_EDGES * 64;

    if (ws_size >= WS_NEEDED) {
        prep_feat16<<<(N_NODES * 32 + 255) / 256, 256, 0, stream>>>(feat, feat16);
        edge_mlp_kernel<<<NBLK, 512, 0, stream>>>(endpoints, edge_len, theta, feat16,
                                                  b1s, b2s, b1v, b2v,
                                                  wt1s, wt1v, wt2s, wt2v,
                                                  w1s192, w1v192, h0, v0);
    } else {
        edge_mlp_kernel_f32<<<NBLK, 512, 0, stream>>>(endpoints, edge_len, theta, feat,
                                                      b1s, b2s, b1v, b2v,
                                                      wt1s, wt1v, wt2s, wt2v,
                                                      w1s192, w1v192, h0, v0);
    }
}